// Round 5
// baseline (670.088 us; speedup 1.0000x reference)
//
#include <hip/hip_runtime.h>
#include <hip/hip_bf16.h>

#define T_DIM   2048
#define B_DIM   64
#define IN_DIM  256
#define H_DIM   256
#define M_TOT   (T_DIM * B_DIM)              // 131072
#define OUT_MAIN ((size_t)M_TOT * H_DIM)     // 33554432

typedef __bf16 bf16x8 __attribute__((ext_vector_type(8)));
typedef float  floatx4 __attribute__((ext_vector_type(4)));

__device__ __forceinline__ unsigned short f2bf(float f) {
    unsigned int u = __float_as_uint(f);
    unsigned int r = u + 0x7FFFu + ((u >> 16) & 1u);
    return (unsigned short)(r >> 16);
}
__device__ __forceinline__ float sigf(float v) {
    return 1.0f / (1.0f + __expf(-v));
}

// ---------------------------------------------------------------------------
// Prep: ghpack[b][h] = {gh_r + b_ih_r, gh_z + b_ih_z, gh_n, hid[b][h]}
//       wsA = w_ih bf16 swizzled into MFMA 16x16x32 A-fragment order
//             (lane&15 -> row n, (lane>>4)*8+j -> k), entry idx
//             ((ntile*8 + kstep)*64 + lane)*8
//       biasn[h] = b_ih[2H + h]
// ---------------------------------------------------------------------------
__global__ void __launch_bounds__(256) gru_prep(
    const float* __restrict__ hid, const float* __restrict__ w_ih,
    const float* __restrict__ w_hh, const float* __restrict__ b_ih,
    const float* __restrict__ b_hh, unsigned short* __restrict__ wsA,
    float4* __restrict__ ghpack, float* __restrict__ biasn)
{
    const int blk = blockIdx.x, tid = threadIdx.x;
    if (blk < 64) {
        const int bb = blk, h = tid;
        const float4* hv4 = (const float4*)(hid + (size_t)bb * H_DIM);
        const float4* w0  = (const float4*)(w_hh + (size_t)h * H_DIM);
        const float4* w1  = (const float4*)(w_hh + (size_t)(H_DIM + h) * H_DIM);
        const float4* w2  = (const float4*)(w_hh + (size_t)(2 * H_DIM + h) * H_DIM);
        float s0 = 0.f, s1 = 0.f, s2 = 0.f;
        for (int k = 0; k < H_DIM / 4; k++) {
            float4 hv = hv4[k];
            float4 a = w0[k]; s0 += hv.x*a.x + hv.y*a.y + hv.z*a.z + hv.w*a.w;
            float4 b = w1[k]; s1 += hv.x*b.x + hv.y*b.y + hv.z*b.z + hv.w*b.w;
            float4 c = w2[k]; s2 += hv.x*c.x + hv.y*c.y + hv.z*c.z + hv.w*c.w;
        }
        float4 o;
        o.x = s0 + b_hh[h]             + b_ih[h];
        o.y = s1 + b_hh[H_DIM + h]     + b_ih[H_DIM + h];
        o.z = s2 + b_hh[2 * H_DIM + h];
        o.w = hid[(size_t)bb * H_DIM + h];
        ghpack[bb * H_DIM + h] = o;
    } else if (blk < 160) {
        const int idx   = (blk - 64) * 256 + tid;   // 0..24575
        const int lane  = idx & 63;
        const int kstep = (idx >> 6) & 7;
        const int ntile = idx >> 9;                 // 0..47 over N=768
        const int n = ntile * 16 + (lane & 15);
        const int k = kstep * 32 + (lane >> 4) * 8;
        const float* src = w_ih + (size_t)n * IN_DIM + k;
        unsigned short* dst = wsA + (size_t)idx * 8;
        #pragma unroll
        for (int j = 0; j < 8; j++) dst[j] = f2bf(src[j]);
    } else {
        biasn[tid] = b_ih[2 * H_DIM + tid];
    }
}

// ---------------------------------------------------------------------------
// Main, barrier-free: A = w_ih (regs, fixed). B fragments loaded DIRECTLY
// from global x (fp32) in fragment order and converted in-register — no LDS
// x tile, no __syncthreads, no block-wide lockstep.
// Block: 256 thr = 4 waves, all same (bq, t-range), wave = 16 h of the
// block's h-quarter -> the 4 waves read identical x tiles (L1 reuse).
// Grid: 64 t-chunks x 4 bq x 4 hq = 1024 blocks, XCD-contiguous mapping.
// C/D: col=lane&15 -> m (b-row), row=(lane>>4)*4+reg -> h.
// NOTE: no min-waves clause in launch_bounds — live set is ~220 VGPR
// (afrag 96 + xf 64 + state). (256,2) would cap at 128 and force scratch
// spills; plain (256) lands at 2 waves/SIMD = 2 blocks/CU, zero spill.
// ---------------------------------------------------------------------------
__global__ void __launch_bounds__(256) gru_main(
    const float* __restrict__ x, const unsigned short* __restrict__ wsA,
    const float4* __restrict__ ghpack, const float* __restrict__ biasn,
    float* __restrict__ out)
{
    __shared__ float epi[4][16 * 20];              // per-wave private transpose tile

    const int tid  = threadIdx.x;
    const int lane = tid & 63;
    const int wid  = tid >> 6;                     // 0..3
    const int lr = lane & 15, lq = lane >> 4;

    // XCD-contiguous: xcd = raw&7 gets wg range [xcd*128, +128) -> the 16
    // blocks sharing one t-chunk's x slice (2 MiB) land on one XCD's L2.
    const int raw = blockIdx.x;
    const int wg  = (raw & 7) * 128 + (raw >> 3);  // 0..1023, bijective
    const int tch = wg >> 4;                       // 0..63, 32 t each
    const int bq  = (wg >> 2) & 3;
    const int hq  = wg & 3;
    const int hbase = hq * 64 + wid * 16;

    // ---- A fragments: w_ih for 3 gates x K=256, fixed for whole block
    bf16x8 afrag[3][8];
    #pragma unroll
    for (int g = 0; g < 3; g++) {
        const int ntile = g * 16 + hq * 4 + wid;
        #pragma unroll
        for (int ks = 0; ks < 8; ks++)
            afrag[g][ks] = *reinterpret_cast<const bf16x8*>(
                wsA + (((size_t)ntile * 8 + ks) * 64 + lane) * 8);
    }
    // ---- per-(b,h) GRU state, fixed for whole block: b = bq*16+lr
    float4 gp[4]; float bn[4];
    #pragma unroll
    for (int reg = 0; reg < 4; reg++) {
        gp[reg] = ghpack[(bq * 16 + lr) * H_DIM + hbase + lq * 4 + reg];
        bn[reg] = biasn[hbase + lq * 4 + reg];
    }

    // lane's fixed position within the x tile: row = bq*16+lr, col = lq*8
    const float* xbase = x + ((size_t)bq * 16 + lr) * IN_DIM + lq * 8;

    #pragma unroll 1
    for (int i = 0; i < 32; i++) {
        const int t = tch * 32 + i;
        const float* xp = xbase + (size_t)t * (B_DIM * IN_DIM);

        // ---- issue all 16 loads first (pipelined in the memory system)
        float4 xf[16];
        #pragma unroll
        for (int ks = 0; ks < 8; ks++) {
            xf[2 * ks]     = *reinterpret_cast<const float4*>(xp + ks * 32);
            xf[2 * ks + 1] = *reinterpret_cast<const float4*>(xp + ks * 32 + 4);
        }

        // ---- convert + MFMA: 3 gates x 8 ksteps, B frag shared across gates
        floatx4 acc0 = {0.f,0.f,0.f,0.f}, acc1 = {0.f,0.f,0.f,0.f}, acc2 = {0.f,0.f,0.f,0.f};
        #pragma unroll
        for (int ks = 0; ks < 8; ks++) {
            const float4 a = xf[2 * ks], b = xf[2 * ks + 1];
            bf16x8 bfrag;
            bfrag[0] = (__bf16)a.x; bfrag[1] = (__bf16)a.y;
            bfrag[2] = (__bf16)a.z; bfrag[3] = (__bf16)a.w;
            bfrag[4] = (__bf16)b.x; bfrag[5] = (__bf16)b.y;
            bfrag[6] = (__bf16)b.z; bfrag[7] = (__bf16)b.w;
            acc0 = __builtin_amdgcn_mfma_f32_16x16x32_bf16(afrag[0][ks], bfrag, acc0, 0, 0, 0);
            acc1 = __builtin_amdgcn_mfma_f32_16x16x32_bf16(afrag[1][ks], bfrag, acc1, 0, 0, 0);
            acc2 = __builtin_amdgcn_mfma_f32_16x16x32_bf16(afrag[2][ks], bfrag, acc2, 0, 0, 0);
        }

        // ---- GRU epilogue in registers: lane m_local=lr, h = hbase+lq*4+reg
        float o[4];
        #pragma unroll
        for (int reg = 0; reg < 4; reg++) {
            const float r = sigf(acc0[reg] + gp[reg].x);
            const float z = sigf(acc1[reg] + gp[reg].y);
            const float e = __expf(-2.0f * (acc2[reg] + bn[reg] + r * gp[reg].z));
            const float n = (1.0f - e) / (1.0f + e);
            o[reg] = (1.0f - z) * n + z * gp[reg].w;
        }

        // ---- transpose via per-wave LDS tile, then coalesced 64B stores
        *reinterpret_cast<float4*>(&epi[wid][lr * 20 + lq * 4]) =
            make_float4(o[0], o[1], o[2], o[3]);
        const int m2 = lane >> 2, hs = lane & 3;
        const float4 ov = *reinterpret_cast<const float4*>(
            &epi[wid][m2 * 20 + hs * 4]);

        const int m0 = t * 64 + bq * 16;
        *reinterpret_cast<float4*>(out + (size_t)(m0 + m2) * H_DIM + hbase + hs * 4) = ov;
        if (t == T_DIM - 1)
            *reinterpret_cast<float4*>(out + OUT_MAIN +
                (size_t)(bq * 16 + m2) * H_DIM + hbase + hs * 4) = ov;

        // loose alignment of the block's 4 waves for L1 tile reuse
        // (raw s_barrier: no waitcnt-drain semantics, no shared data)
        if ((i & 7) == 7) __builtin_amdgcn_s_barrier();
    }
}

extern "C" void kernel_launch(void* const* d_in, const int* in_sizes, int n_in,
                              void* d_out, int out_size, void* d_ws, size_t ws_size,
                              hipStream_t stream) {
    const float* x    = (const float*)d_in[0];
    const float* hid  = (const float*)d_in[1];
    const float* w_ih = (const float*)d_in[2];
    const float* w_hh = (const float*)d_in[3];
    const float* b_ih = (const float*)d_in[4];
    const float* b_hh = (const float*)d_in[5];
    float* out = (float*)d_out;

    char* ws = (char*)d_ws;
    unsigned short* wsA = (unsigned short*)ws;              // 393216 B
    float4* ghpack = (float4*)(ws + 393216);                // 262144 B
    float*  biasn  = (float*)(ws + 393216 + 262144);        // 1024 B

    gru_prep<<<161, 256, 0, stream>>>(hid, w_ih, w_hh, b_ih, b_hh, wsA, ghpack, biasn);
    gru_main<<<1024, 256, 0, stream>>>(x, wsA, ghpack, biasn, out);
}

// Round 9
// 477.454 us; speedup vs baseline: 1.4035x; 1.4035x over previous
//
#include <hip/hip_runtime.h>
#include <hip/hip_bf16.h>

#define T_DIM   2048
#define B_DIM   64
#define IN_DIM  256
#define H_DIM   256
#define M_TOT   (T_DIM * B_DIM)              // 131072
#define OUT_MAIN ((size_t)M_TOT * H_DIM)     // 33554432

typedef __bf16 bf16x8 __attribute__((ext_vector_type(8)));
typedef float  floatx4 __attribute__((ext_vector_type(4)));

__device__ __forceinline__ unsigned short f2bf(float f) {
    unsigned int u = __float_as_uint(f);
    unsigned int r = u + 0x7FFFu + ((u >> 16) & 1u);
    return (unsigned short)(r >> 16);
}
__device__ __forceinline__ float sigf(float v) {
    return 1.0f / (1.0f + __expf(-v));
}

// ---------------------------------------------------------------------------
// Prep: ghpack[b][h] = {gh_r + b_ih_r, gh_z + b_ih_z, gh_n, hid[b][h]}
//       wsA = w_ih bf16 swizzled into MFMA 16x16x32 A-fragment order
//             (lane&15 -> row n, (lane>>4)*8+j -> k), entry idx
//             ((ntile*8 + kstep)*64 + lane)*8
//       biasn[h] = b_ih[2H + h]
// ---------------------------------------------------------------------------
__global__ void __launch_bounds__(256) gru_prep(
    const float* __restrict__ hid, const float* __restrict__ w_ih,
    const float* __restrict__ w_hh, const float* __restrict__ b_ih,
    const float* __restrict__ b_hh, unsigned short* __restrict__ wsA,
    float4* __restrict__ ghpack, float* __restrict__ biasn)
{
    const int blk = blockIdx.x, tid = threadIdx.x;
    if (blk < 64) {
        const int bb = blk, h = tid;
        const float4* hv4 = (const float4*)(hid + (size_t)bb * H_DIM);
        const float4* w0  = (const float4*)(w_hh + (size_t)h * H_DIM);
        const float4* w1  = (const float4*)(w_hh + (size_t)(H_DIM + h) * H_DIM);
        const float4* w2  = (const float4*)(w_hh + (size_t)(2 * H_DIM + h) * H_DIM);
        float s0 = 0.f, s1 = 0.f, s2 = 0.f;
        for (int k = 0; k < H_DIM / 4; k++) {
            float4 hv = hv4[k];
            float4 a = w0[k]; s0 += hv.x*a.x + hv.y*a.y + hv.z*a.z + hv.w*a.w;
            float4 b = w1[k]; s1 += hv.x*b.x + hv.y*b.y + hv.z*b.z + hv.w*b.w;
            float4 c = w2[k]; s2 += hv.x*c.x + hv.y*c.y + hv.z*c.z + hv.w*c.w;
        }
        float4 o;
        o.x = s0 + b_hh[h]             + b_ih[h];
        o.y = s1 + b_hh[H_DIM + h]     + b_ih[H_DIM + h];
        o.z = s2 + b_hh[2 * H_DIM + h];
        o.w = hid[(size_t)bb * H_DIM + h];
        ghpack[bb * H_DIM + h] = o;
    } else if (blk < 160) {
        const int idx   = (blk - 64) * 256 + tid;   // 0..24575
        const int lane  = idx & 63;
        const int kstep = (idx >> 6) & 7;
        const int ntile = idx >> 9;                 // 0..47 over N=768
        const int n = ntile * 16 + (lane & 15);
        const int k = kstep * 32 + (lane >> 4) * 8;
        const float* src = w_ih + (size_t)n * IN_DIM + k;
        unsigned short* dst = wsA + (size_t)idx * 8;
        #pragma unroll
        for (int j = 0; j < 8; j++) dst[j] = f2bf(src[j]);
    } else {
        biasn[tid] = b_ih[2 * H_DIM + tid];
    }
}

// ---------------------------------------------------------------------------
// Main, barrier-free: A = w_ih (regs, fixed). B fragments loaded DIRECTLY
// from global x (fp32) in fragment order and converted in-register — no LDS
// x tile, no __syncthreads, no block-wide lockstep.
// Block: 256 thr = 4 waves, all same (bq, t-range), wave = 16 h of the
// block's h-quarter -> the 4 waves read identical x tiles (L1/L2 reuse;
// CONFIRMED round 5: FETCH 70 MB << 128 MB logical, L2 absorbs sharing).
// Grid: 64 t-chunks x 4 bq x 4 hq = 1024 blocks, XCD-contiguous mapping.
// C/D: col=lane&15 -> m (b-row), row=(lane>>4)*4+reg -> h.
//
// __launch_bounds__(256, 2): min 2 waves/EU -> VGPR cap = 512/2 = 256,
// which FITS the ~220-reg live set (afrag 96 + xf 64 + state).
// MEASURED round 5: without the min-waves clause hipcc targets high
// occupancy, allocates 84 VGPRs, demotes afrag to per-iter reloads and
// serializes the load burst -> 500 us latency-bound (MfmaUtil 4%).
// The clause pins the allocator at 2 waves/SIMD with everything resident.
// ---------------------------------------------------------------------------
__global__ void __launch_bounds__(256, 2) gru_main(
    const float* __restrict__ x, const unsigned short* __restrict__ wsA,
    const float4* __restrict__ ghpack, const float* __restrict__ biasn,
    float* __restrict__ out)
{
    __shared__ float epi[4][16 * 20];              // per-wave private transpose tile

    const int tid  = threadIdx.x;
    const int lane = tid & 63;
    const int wid  = tid >> 6;                     // 0..3
    const int lr = lane & 15, lq = lane >> 4;

    // XCD-contiguous: xcd = raw&7 gets wg range [xcd*128, +128) -> the 16
    // blocks sharing one t-chunk's x slice (2 MiB) land on one XCD's L2.
    const int raw = blockIdx.x;
    const int wg  = (raw & 7) * 128 + (raw >> 3);  // 0..1023, bijective
    const int tch = wg >> 4;                       // 0..63, 32 t each
    const int bq  = (wg >> 2) & 3;
    const int hq  = wg & 3;
    const int hbase = hq * 64 + wid * 16;

    // ---- A fragments: w_ih for 3 gates x K=256, fixed for whole block
    bf16x8 afrag[3][8];
    #pragma unroll
    for (int g = 0; g < 3; g++) {
        const int ntile = g * 16 + hq * 4 + wid;
        #pragma unroll
        for (int ks = 0; ks < 8; ks++)
            afrag[g][ks] = *reinterpret_cast<const bf16x8*>(
                wsA + (((size_t)ntile * 8 + ks) * 64 + lane) * 8);
    }
    // ---- per-(b,h) GRU state, fixed for whole block: b = bq*16+lr
    float4 gp[4]; float bn[4];
    #pragma unroll
    for (int reg = 0; reg < 4; reg++) {
        gp[reg] = ghpack[(bq * 16 + lr) * H_DIM + hbase + lq * 4 + reg];
        bn[reg] = biasn[hbase + lq * 4 + reg];
    }

    // lane's fixed position within the x tile: row = bq*16+lr, col = lq*8
    const float* xbase = x + ((size_t)bq * 16 + lr) * IN_DIM + lq * 8;

    #pragma unroll 1
    for (int i = 0; i < 32; i++) {
        const int t = tch * 32 + i;
        const float* xp = xbase + (size_t)t * (B_DIM * IN_DIM);

        // ---- issue all 16 loads first (pipelined in the memory system)
        float4 xf[16];
        #pragma unroll
        for (int ks = 0; ks < 8; ks++) {
            xf[2 * ks]     = *reinterpret_cast<const float4*>(xp + ks * 32);
            xf[2 * ks + 1] = *reinterpret_cast<const float4*>(xp + ks * 32 + 4);
        }

        // ---- convert + MFMA: 3 gates x 8 ksteps, B frag shared across gates
        floatx4 acc0 = {0.f,0.f,0.f,0.f}, acc1 = {0.f,0.f,0.f,0.f}, acc2 = {0.f,0.f,0.f,0.f};
        #pragma unroll
        for (int ks = 0; ks < 8; ks++) {
            const float4 a = xf[2 * ks], b = xf[2 * ks + 1];
            bf16x8 bfrag;
            bfrag[0] = (__bf16)a.x; bfrag[1] = (__bf16)a.y;
            bfrag[2] = (__bf16)a.z; bfrag[3] = (__bf16)a.w;
            bfrag[4] = (__bf16)b.x; bfrag[5] = (__bf16)b.y;
            bfrag[6] = (__bf16)b.z; bfrag[7] = (__bf16)b.w;
            acc0 = __builtin_amdgcn_mfma_f32_16x16x32_bf16(afrag[0][ks], bfrag, acc0, 0, 0, 0);
            acc1 = __builtin_amdgcn_mfma_f32_16x16x32_bf16(afrag[1][ks], bfrag, acc1, 0, 0, 0);
            acc2 = __builtin_amdgcn_mfma_f32_16x16x32_bf16(afrag[2][ks], bfrag, acc2, 0, 0, 0);
        }

        // ---- GRU epilogue in registers: lane m_local=lr, h = hbase+lq*4+reg
        float o[4];
        #pragma unroll
        for (int reg = 0; reg < 4; reg++) {
            const float r = sigf(acc0[reg] + gp[reg].x);
            const float z = sigf(acc1[reg] + gp[reg].y);
            const float e = __expf(-2.0f * (acc2[reg] + bn[reg] + r * gp[reg].z));
            const float n = (1.0f - e) / (1.0f + e);
            o[reg] = (1.0f - z) * n + z * gp[reg].w;
        }

        // ---- transpose via per-wave LDS tile, then coalesced 64B stores
        *reinterpret_cast<float4*>(&epi[wid][lr * 20 + lq * 4]) =
            make_float4(o[0], o[1], o[2], o[3]);
        const int m2 = lane >> 2, hs = lane & 3;
        const float4 ov = *reinterpret_cast<const float4*>(
            &epi[wid][m2 * 20 + hs * 4]);

        const int m0 = t * 64 + bq * 16;
        *reinterpret_cast<float4*>(out + (size_t)(m0 + m2) * H_DIM + hbase + hs * 4) = ov;
        if (t == T_DIM - 1)
            *reinterpret_cast<float4*>(out + OUT_MAIN +
                (size_t)(bq * 16 + m2) * H_DIM + hbase + hs * 4) = ov;

        // loose alignment of the block's 4 waves for L1 tile reuse
        // (raw s_barrier: no waitcnt-drain semantics, no shared data)
        if ((i & 7) == 7) __builtin_amdgcn_s_barrier();
    }
}

extern "C" void kernel_launch(void* const* d_in, const int* in_sizes, int n_in,
                              void* d_out, int out_size, void* d_ws, size_t ws_size,
                              hipStream_t stream) {
    const float* x    = (const float*)d_in[0];
    const float* hid  = (const float*)d_in[1];
    const float* w_ih = (const float*)d_in[2];
    const float* w_hh = (const float*)d_in[3];
    const float* b_ih = (const float*)d_in[4];
    const float* b_hh = (const float*)d_in[5];
    float* out = (float*)d_out;

    char* ws = (char*)d_ws;
    unsigned short* wsA = (unsigned short*)ws;              // 393216 B
    float4* ghpack = (float4*)(ws + 393216);                // 262144 B
    float*  biasn  = (float*)(ws + 393216 + 262144);        // 1024 B

    gru_prep<<<161, 256, 0, stream>>>(hid, w_ih, w_hh, b_ih, b_hh, wsA, ghpack, biasn);
    gru_main<<<1024, 256, 0, stream>>>(x, wsA, ghpack, biasn, out);
}